// Round 1
// baseline (1143.983 us; speedup 1.0000x reference)
//
#include <hip/hip_runtime.h>
#include <hip/hip_bf16.h>
#include <math.h>

#define DIMD 1024
#define HIDDEN 4096
#define NE 8
#define TOPK_ 2
#define T_TOKENS 8192
#define NROWS (T_TOKENS * TOPK_)   // 16384 assignment rows (always exactly T*K)
#define BM 128
#define BN 128
#define BKK 64
#define MAXTILES (NROWS / BM + NE) // 136 upper bound on sum ceil(n_e/BM)

typedef __bf16 bf16_t;
typedef __bf16 bf16x8 __attribute__((ext_vector_type(8)));
typedef float f32x4 __attribute__((ext_vector_type(4)));

// ---------------- router: fp64 accum for tie-safe top-k vs float64 np ref ----------------
__global__ __launch_bounds__(256) void router_kernel(
    const float* __restrict__ x, const float* __restrict__ Wr, const float* __restrict__ br,
    float* __restrict__ logits, float* __restrict__ probs,
    float* __restrict__ tidx, float* __restrict__ tprob,
    int* __restrict__ cnt)
{
    int wave = threadIdx.x >> 6;
    int lane = threadIdx.x & 63;
    int t = blockIdx.x * 4 + wave;
    if (t >= T_TOKENS) return;
    const float* xr = x + (size_t)t * DIMD;
    double acc[NE];
#pragma unroll
    for (int e = 0; e < NE; ++e) acc[e] = 0.0;
    for (int i = 0; i < DIMD / 64; ++i) {
        int d = i * 64 + lane;
        double xv = (double)xr[d];
        const float* wrow = Wr + d * NE;
#pragma unroll
        for (int e = 0; e < NE; ++e) acc[e] += xv * (double)wrow[e];
    }
#pragma unroll
    for (int s = 32; s >= 1; s >>= 1) {
#pragma unroll
        for (int e = 0; e < NE; ++e) acc[e] += __shfl_xor(acc[e], s, 64);
    }
    if (lane == 0) {
        double lg[NE], mx = -1e300;
#pragma unroll
        for (int e = 0; e < NE; ++e) { lg[e] = acc[e] + (double)br[e]; mx = fmax(mx, lg[e]); }
        double pe[NE], s = 0.0;
#pragma unroll
        for (int e = 0; e < NE; ++e) { pe[e] = exp(lg[e] - mx); s += pe[e]; }
        double inv = 1.0 / s;
        int i0 = 0; double p0 = -1.0;
#pragma unroll
        for (int e = 0; e < NE; ++e) { pe[e] *= inv; if (pe[e] > p0) { p0 = pe[e]; i0 = e; } }
        int i1 = 0; double p1 = -1.0;
#pragma unroll
        for (int e = 0; e < NE; ++e) { if (e == i0) continue; if (pe[e] > p1) { p1 = pe[e]; i1 = e; } }
#pragma unroll
        for (int e = 0; e < NE; ++e) {
            logits[t * NE + e] = (float)lg[e];
            probs[t * NE + e] = (float)pe[e];
        }
        tidx[t * 2 + 0] = (float)i0; tidx[t * 2 + 1] = (float)i1;
        tprob[t * 2 + 0] = (float)p0; tprob[t * 2 + 1] = (float)p1;
        atomicAdd(&cnt[i0], 1); atomicAdd(&cnt[i1], 1);
    }
}

// ---------------- transpose + fp32->bf16: in [E][K][N] f32 -> out [E][N][K] bf16 ----------------
__global__ __launch_bounds__(256) void transpose_kernel(
    const float* __restrict__ in, bf16_t* __restrict__ out, int K, int N)
{
    __shared__ float tile[32][33];
    int e = blockIdx.z;
    int k0 = blockIdx.x * 32;
    int n0 = blockIdx.y * 32;
    const float* ip = in + (size_t)e * K * N;
    bf16_t* op = out + (size_t)e * N * K;
    int tr = threadIdx.x >> 5;   // 0..7
    int tc = threadIdx.x & 31;
#pragma unroll
    for (int i = 0; i < 4; ++i) {
        int r = tr + i * 8;
        tile[r][tc] = ip[(size_t)(k0 + r) * N + (n0 + tc)];
    }
    __syncthreads();
#pragma unroll
    for (int i = 0; i < 4; ++i) {
        int r = tr + i * 8;
        op[(size_t)(n0 + r) * K + (k0 + tc)] = (bf16_t)tile[tc][r];
    }
}

// ---------------- prefix sums + tile descriptors (1 thread; trivial work) ----------------
__global__ void prefix_kernel(const int* __restrict__ cnt, int* __restrict__ offsets,
                              int* __restrict__ cursor, int* __restrict__ tileE,
                              int* __restrict__ tileRow, int* __restrict__ numTiles)
{
    if (threadIdx.x == 0 && blockIdx.x == 0) {
        int off = 0;
        for (int e = 0; e < NE; ++e) { offsets[e] = off; off += cnt[e]; cursor[e] = 0; }
        offsets[NE] = off;
        int nt = 0;
        for (int e = 0; e < NE; ++e)
            for (int s = 0; s < cnt[e]; s += BM) { tileE[nt] = e; tileRow[nt] = offsets[e] + s; ++nt; }
        *numTiles = nt;
    }
}

// ---------------- scatter tokens into expert-grouped row lists ----------------
__global__ __launch_bounds__(256) void scatter_kernel(
    const float* __restrict__ tidx, const float* __restrict__ tprob,
    const int* __restrict__ offsets, int* __restrict__ cursor,
    int* __restrict__ rowToken, float* __restrict__ rowProb)
{
    int t = blockIdx.x * 256 + threadIdx.x;
    if (t >= T_TOKENS) return;
#pragma unroll
    for (int k = 0; k < TOPK_; ++k) {
        int e = (int)tidx[t * 2 + k];
        float p = tprob[t * 2 + k];
        int pos = atomicAdd(&cursor[e], 1);
        int r = offsets[e] + pos;
        rowToken[r] = t;
        rowProb[r] = p;
    }
}

// ---------------- pass 1: h = gelu(Xg @ W1 + b1), bf16 MFMA ----------------
__global__ __launch_bounds__(256) void ffn1_kernel(
    const float* __restrict__ x, const bf16_t* __restrict__ W1T, const float* __restrict__ b1,
    const int* __restrict__ tileE, const int* __restrict__ tileRow, const int* __restrict__ numTiles,
    const int* __restrict__ offsets, const int* __restrict__ rowToken,
    bf16_t* __restrict__ h, int hc_base, int hc_len)
{
    int tile = blockIdx.x;
    if (tile >= *numTiles) return;
    int e = tileE[tile];
    int row0 = tileRow[tile];
    int rend = offsets[e + 1];
    int n0 = blockIdx.y * BN;          // chunk-local column base
    int nglob = hc_base + n0;          // global hidden column base

    __shared__ bf16_t As[BM][BKK + 8];
    __shared__ bf16_t Bs[BN][BKK + 8];

    int tid = threadIdx.x;
    int lane = tid & 63;
    int wid = tid >> 6;
    int wr = (wid >> 1) * 64;
    int wc = (wid & 1) * 64;

    f32x4 acc[4][4];
#pragma unroll
    for (int i = 0; i < 4; ++i)
#pragma unroll
        for (int j = 0; j < 4; ++j) acc[i][j] = f32x4{0.f, 0.f, 0.f, 0.f};

    int sr = tid >> 1;            // 0..127
    int sc = (tid & 1) * 32;      // 0 or 32
    int arow = row0 + sr;
    int aidx = arow < NROWS ? arow : (NROWS - 1);
    int tok = rowToken[aidx];
    const float* xrow = x + (size_t)tok * DIMD;
    const bf16_t* brow = W1T + ((size_t)e * HIDDEN + (nglob + sr)) * DIMD;

    for (int k0 = 0; k0 < DIMD; k0 += BKK) {
        // A stage: gather + fp32->bf16 (32 elems/thread)
#pragma unroll
        for (int i = 0; i < 4; ++i) {
            float4 v = *reinterpret_cast<const float4*>(xrow + k0 + sc + i * 8);
            float4 v2 = *reinterpret_cast<const float4*>(xrow + k0 + sc + i * 8 + 4);
            bf16x8 b;
            b[0] = (bf16_t)v.x;  b[1] = (bf16_t)v.y;  b[2] = (bf16_t)v.z;  b[3] = (bf16_t)v.w;
            b[4] = (bf16_t)v2.x; b[5] = (bf16_t)v2.y; b[6] = (bf16_t)v2.z; b[7] = (bf16_t)v2.w;
            *reinterpret_cast<bf16x8*>(&As[sr][sc + i * 8]) = b;
        }
        // B stage: bf16 direct (32 elems/thread)
#pragma unroll
        for (int i = 0; i < 4; ++i) {
            bf16x8 b = *reinterpret_cast<const bf16x8*>(brow + k0 + sc + i * 8);
            *reinterpret_cast<bf16x8*>(&Bs[sr][sc + i * 8]) = b;
        }
        __syncthreads();
#pragma unroll
        for (int ks = 0; ks < BKK; ks += 32) {
            int kk = ks + (lane >> 4) * 8;
            int rr = lane & 15;
            bf16x8 af[4], bfr[4];
#pragma unroll
            for (int m = 0; m < 4; ++m) af[m] = *reinterpret_cast<const bf16x8*>(&As[wr + m * 16 + rr][kk]);
#pragma unroll
            for (int n = 0; n < 4; ++n) bfr[n] = *reinterpret_cast<const bf16x8*>(&Bs[wc + n * 16 + rr][kk]);
#pragma unroll
            for (int m = 0; m < 4; ++m)
#pragma unroll
                for (int n = 0; n < 4; ++n)
                    acc[m][n] = __builtin_amdgcn_mfma_f32_16x16x32_bf16(af[m], bfr[n], acc[m][n], 0, 0, 0);
        }
        __syncthreads();
    }

    // epilogue: +bias, exact-erf GELU, store bf16 h
    int crow = (lane >> 4) * 4;
    int ccol = lane & 15;
#pragma unroll
    for (int m = 0; m < 4; ++m) {
#pragma unroll
        for (int n = 0; n < 4; ++n) {
            int col = wc + n * 16 + ccol;
            float bias = b1[e * HIDDEN + nglob + col];
#pragma unroll
            for (int r = 0; r < 4; ++r) {
                int row = row0 + wr + m * 16 + crow + r;
                if (row < rend) {
                    float v = acc[m][n][r] + bias;
                    float g = 0.5f * v * (1.0f + erff(v * 0.70710678118654752f));
                    h[(size_t)row * hc_len + n0 + col] = (bf16_t)g;
                }
            }
        }
    }
}

// ---------------- pass 2: mixed += p * (Hg @ W2 + b2), atomic scatter ----------------
__global__ __launch_bounds__(256) void ffn2_kernel(
    const bf16_t* __restrict__ h, const bf16_t* __restrict__ W2T, const float* __restrict__ b2,
    const int* __restrict__ tileE, const int* __restrict__ tileRow, const int* __restrict__ numTiles,
    const int* __restrict__ offsets, const int* __restrict__ rowToken, const float* __restrict__ rowProb,
    float* __restrict__ mixed, int hc_base, int hc_len, int add_bias)
{
    int tile = blockIdx.x;
    if (tile >= *numTiles) return;
    int e = tileE[tile];
    int row0 = tileRow[tile];
    int rend = offsets[e + 1];
    int n0 = blockIdx.y * BN;    // output d column base

    __shared__ bf16_t As[BM][BKK + 8];
    __shared__ bf16_t Bs[BN][BKK + 8];

    int tid = threadIdx.x;
    int lane = tid & 63;
    int wid = tid >> 6;
    int wr = (wid >> 1) * 64;
    int wc = (wid & 1) * 64;

    f32x4 acc[4][4];
#pragma unroll
    for (int i = 0; i < 4; ++i)
#pragma unroll
        for (int j = 0; j < 4; ++j) acc[i][j] = f32x4{0.f, 0.f, 0.f, 0.f};

    int sr = tid >> 1;
    int sc = (tid & 1) * 32;
    int arow = row0 + sr;
    int aidx = arow < NROWS ? arow : (NROWS - 1);
    const bf16_t* hrow = h + (size_t)aidx * hc_len;
    const bf16_t* brow = W2T + ((size_t)e * DIMD + (n0 + sr)) * HIDDEN + hc_base;

    for (int k0 = 0; k0 < hc_len; k0 += BKK) {
#pragma unroll
        for (int i = 0; i < 4; ++i) {
            bf16x8 a = *reinterpret_cast<const bf16x8*>(hrow + k0 + sc + i * 8);
            *reinterpret_cast<bf16x8*>(&As[sr][sc + i * 8]) = a;
        }
#pragma unroll
        for (int i = 0; i < 4; ++i) {
            bf16x8 b = *reinterpret_cast<const bf16x8*>(brow + k0 + sc + i * 8);
            *reinterpret_cast<bf16x8*>(&Bs[sr][sc + i * 8]) = b;
        }
        __syncthreads();
#pragma unroll
        for (int ks = 0; ks < BKK; ks += 32) {
            int kk = ks + (lane >> 4) * 8;
            int rr = lane & 15;
            bf16x8 af[4], bfr[4];
#pragma unroll
            for (int m = 0; m < 4; ++m) af[m] = *reinterpret_cast<const bf16x8*>(&As[wr + m * 16 + rr][kk]);
#pragma unroll
            for (int n = 0; n < 4; ++n) bfr[n] = *reinterpret_cast<const bf16x8*>(&Bs[wc + n * 16 + rr][kk]);
#pragma unroll
            for (int m = 0; m < 4; ++m)
#pragma unroll
                for (int n = 0; n < 4; ++n)
                    acc[m][n] = __builtin_amdgcn_mfma_f32_16x16x32_bf16(af[m], bfr[n], acc[m][n], 0, 0, 0);
        }
        __syncthreads();
    }

    int crow = (lane >> 4) * 4;
    int ccol = lane & 15;
#pragma unroll
    for (int m = 0; m < 4; ++m) {
#pragma unroll
        for (int n = 0; n < 4; ++n) {
            int col = wc + n * 16 + ccol;
            int dcol = n0 + col;
            float bias = add_bias ? b2[e * DIMD + dcol] : 0.f;
#pragma unroll
            for (int r = 0; r < 4; ++r) {
                int row = row0 + wr + m * 16 + crow + r;
                if (row < rend) {
                    float v = acc[m][n][r] + bias;
                    float p = rowProb[row];
                    int tok = rowToken[row];
                    atomicAdd(&mixed[(size_t)tok * DIMD + dcol], p * v);
                }
            }
        }
    }
}

extern "C" void kernel_launch(void* const* d_in, const int* in_sizes, int n_in,
                              void* d_out, int out_size, void* d_ws, size_t ws_size,
                              hipStream_t stream)
{
    const float* x  = (const float*)d_in[0];
    const float* Wr = (const float*)d_in[1];
    const float* br = (const float*)d_in[2];
    const float* W1 = (const float*)d_in[3];
    const float* b1 = (const float*)d_in[4];
    const float* W2 = (const float*)d_in[5];
    const float* b2 = (const float*)d_in[6];

    float* out = (float*)d_out;
    float* mixed  = out;                                   // [8192][1024]
    float* logits = out + (size_t)T_TOKENS * DIMD;         // [8192][8]
    float* probs  = logits + T_TOKENS * NE;                // [8192][8]
    float* tidx   = probs + T_TOKENS * NE;                 // [8192][2] as float
    float* tprob  = tidx + T_TOKENS * TOPK_;               // [8192][2]

    char* p = (char*)d_ws;
    auto alloc = [&](size_t bytes) { char* r = p; p += (bytes + 255) & ~255ull; return r; };
    int*    cnt      = (int*)alloc(NE * 4);
    int*    offsets  = (int*)alloc((NE + 1) * 4);
    int*    cursor   = (int*)alloc(NE * 4);
    int*    numTiles = (int*)alloc(4);
    int*    tileE    = (int*)alloc(MAXTILES * 4);
    int*    tileRow  = (int*)alloc(MAXTILES * 4);
    int*    rowToken = (int*)alloc(NROWS * 4);
    float*  rowProb  = (float*)alloc(NROWS * 4);
    bf16_t* W1T      = (bf16_t*)alloc((size_t)NE * HIDDEN * DIMD * 2);
    bf16_t* W2T      = (bf16_t*)alloc((size_t)NE * DIMD * HIDDEN * 2);
    size_t used = (size_t)(p - (char*)d_ws);
    size_t remain = ws_size > used ? ws_size - used : 0;
    int hc = HIDDEN;
    while (hc > 512 && (size_t)NROWS * hc * 2 > remain) hc >>= 1;
    bf16_t* hbuf = (bf16_t*)alloc((size_t)NROWS * hc * 2);

    hipMemsetAsync(mixed, 0, (size_t)T_TOKENS * DIMD * 4, stream);
    hipMemsetAsync(cnt, 0, NE * 4, stream);

    router_kernel<<<T_TOKENS / 4, 256, 0, stream>>>(x, Wr, br, logits, probs, tidx, tprob, cnt);
    transpose_kernel<<<dim3(DIMD / 32, HIDDEN / 32, NE), 256, 0, stream>>>(W1, W1T, DIMD, HIDDEN);
    transpose_kernel<<<dim3(HIDDEN / 32, DIMD / 32, NE), 256, 0, stream>>>(W2, W2T, HIDDEN, DIMD);
    prefix_kernel<<<1, 64, 0, stream>>>(cnt, offsets, cursor, tileE, tileRow, numTiles);
    scatter_kernel<<<T_TOKENS / 256, 256, 0, stream>>>(tidx, tprob, offsets, cursor, rowToken, rowProb);

    for (int c0 = 0; c0 < HIDDEN; c0 += hc) {
        ffn1_kernel<<<dim3(MAXTILES, hc / BN), 256, 0, stream>>>(
            x, W1T, b1, tileE, tileRow, numTiles, offsets, rowToken, hbuf, c0, hc);
        ffn2_kernel<<<dim3(MAXTILES, DIMD / BN), 256, 0, stream>>>(
            hbuf, W2T, b2, tileE, tileRow, numTiles, offsets, rowToken, rowProb,
            mixed, c0, hc, c0 == 0 ? 1 : 0);
    }
}

// Round 2
// 943.415 us; speedup vs baseline: 1.2126x; 1.2126x over previous
//
#include <hip/hip_runtime.h>
#include <hip/hip_bf16.h>
#include <math.h>
#include <stdint.h>

#define DIMD 1024
#define HIDDEN 4096
#define NE 8
#define TOPK_ 2
#define T_TOKENS 8192
#define NROWS (T_TOKENS * TOPK_)   // 16384 assignment rows
#define BM 128
#define BN 128
#define BK 64
#define MAXTILES (NROWS / BM + NE) // 136 upper bound

typedef __bf16 bf16_t;
typedef __bf16 bf16x8 __attribute__((ext_vector_type(8)));
typedef __bf16 bf16x4v __attribute__((ext_vector_type(4)));
typedef float f32x4 __attribute__((ext_vector_type(4)));

// async global->LDS, 16B per lane; lds ptr must be wave-uniform
__device__ __forceinline__ void glds16(const void* g, void* l) {
    __builtin_amdgcn_global_load_lds(
        (const __attribute__((address_space(1))) unsigned int*)g,
        (__attribute__((address_space(3))) unsigned int*)l, 16, 0, 0);
}

// swizzled fragment read: LDS tile is [row][64 bf16] linear, 128B rows,
// 16B chunk c holds global chunk c^(row&7)  (source pre-swizzled to match)
__device__ __forceinline__ bf16x8 ldfrag(const char* lds, int row, int kelem) {
    int byte = row * 128 + ((kelem * 2) ^ ((row & 7) << 4));
    return *reinterpret_cast<const bf16x8*>(lds + byte);
}

// ---------------- router: fp64 accum for tie-safe top-k ----------------
__global__ __launch_bounds__(256) void router_kernel(
    const float* __restrict__ x, const float* __restrict__ Wr, const float* __restrict__ br,
    float* __restrict__ logits, float* __restrict__ probs,
    float* __restrict__ tidx, float* __restrict__ tprob,
    int* __restrict__ cnt)
{
    int wave = threadIdx.x >> 6;
    int lane = threadIdx.x & 63;
    int t = blockIdx.x * 4 + wave;
    if (t >= T_TOKENS) return;
    const float* xr = x + (size_t)t * DIMD;
    double acc[NE];
#pragma unroll
    for (int e = 0; e < NE; ++e) acc[e] = 0.0;
    for (int i = 0; i < DIMD / 64; ++i) {
        int d = i * 64 + lane;
        double xv = (double)xr[d];
        const float* wrow = Wr + d * NE;
#pragma unroll
        for (int e = 0; e < NE; ++e) acc[e] += xv * (double)wrow[e];
    }
#pragma unroll
    for (int s = 32; s >= 1; s >>= 1) {
#pragma unroll
        for (int e = 0; e < NE; ++e) acc[e] += __shfl_xor(acc[e], s, 64);
    }
    if (lane == 0) {
        double lg[NE], mx = -1e300;
#pragma unroll
        for (int e = 0; e < NE; ++e) { lg[e] = acc[e] + (double)br[e]; mx = fmax(mx, lg[e]); }
        double pe[NE], s = 0.0;
#pragma unroll
        for (int e = 0; e < NE; ++e) { pe[e] = exp(lg[e] - mx); s += pe[e]; }
        double inv = 1.0 / s;
        int i0 = 0; double p0 = -1.0;
#pragma unroll
        for (int e = 0; e < NE; ++e) { pe[e] *= inv; if (pe[e] > p0) { p0 = pe[e]; i0 = e; } }
        int i1 = 0; double p1 = -1.0;
#pragma unroll
        for (int e = 0; e < NE; ++e) { if (e == i0) continue; if (pe[e] > p1) { p1 = pe[e]; i1 = e; } }
#pragma unroll
        for (int e = 0; e < NE; ++e) {
            logits[t * NE + e] = (float)lg[e];
            probs[t * NE + e] = (float)pe[e];
        }
        tidx[t * 2 + 0] = (float)i0; tidx[t * 2 + 1] = (float)i1;
        tprob[t * 2 + 0] = (float)p0; tprob[t * 2 + 1] = (float)p1;
        atomicAdd(&cnt[i0], 1); atomicAdd(&cnt[i1], 1);
    }
}

// ---------------- x fp32 -> bf16 ----------------
__global__ __launch_bounds__(256) void xconv_kernel(const float* __restrict__ x, bf16_t* __restrict__ Xb)
{
    size_t i = ((size_t)blockIdx.x * 256 + threadIdx.x) * 8;
    if (i >= (size_t)T_TOKENS * DIMD) return;
    float4 a = *reinterpret_cast<const float4*>(x + i);
    float4 b = *reinterpret_cast<const float4*>(x + i + 4);
    bf16x8 o;
    o[0] = (bf16_t)a.x; o[1] = (bf16_t)a.y; o[2] = (bf16_t)a.z; o[3] = (bf16_t)a.w;
    o[4] = (bf16_t)b.x; o[5] = (bf16_t)b.y; o[6] = (bf16_t)b.z; o[7] = (bf16_t)b.w;
    *reinterpret_cast<bf16x8*>(Xb + i) = o;
}

// ---------------- transpose + fp32->bf16: in [E][K][N] f32 -> out [E][N][K] bf16 ----------------
__global__ __launch_bounds__(256) void transpose_kernel(
    const float* __restrict__ in, bf16_t* __restrict__ out, int K, int N)
{
    __shared__ float tile[32][33];
    int e = blockIdx.z;
    int k0 = blockIdx.x * 32;
    int n0 = blockIdx.y * 32;
    const float* ip = in + (size_t)e * K * N;
    bf16_t* op = out + (size_t)e * N * K;
    int t = threadIdx.x;
    int r = t >> 3;            // 0..31
    int c4 = (t & 7) * 4;      // 0..28
    float4 v = *reinterpret_cast<const float4*>(ip + (size_t)(k0 + r) * N + n0 + c4);
    tile[r][c4] = v.x; tile[r][c4 + 1] = v.y; tile[r][c4 + 2] = v.z; tile[r][c4 + 3] = v.w;
    __syncthreads();
    int nn = t >> 3;           // 0..31
    int kk = (t & 7) * 4;      // 0..28
    bf16x4v o;
    o[0] = (bf16_t)tile[kk][nn];
    o[1] = (bf16_t)tile[kk + 1][nn];
    o[2] = (bf16_t)tile[kk + 2][nn];
    o[3] = (bf16_t)tile[kk + 3][nn];
    *reinterpret_cast<bf16x4v*>(op + (size_t)(n0 + nn) * K + k0 + kk) = o;
}

// ---------------- prefix sums + tile descriptors ----------------
__global__ void prefix_kernel(const int* __restrict__ cnt, int* __restrict__ offsets,
                              int* __restrict__ cursor, int* __restrict__ tileE,
                              int* __restrict__ tileRow, int* __restrict__ numTiles)
{
    if (threadIdx.x == 0 && blockIdx.x == 0) {
        int off = 0;
        for (int e = 0; e < NE; ++e) { offsets[e] = off; off += cnt[e]; cursor[e] = 0; }
        offsets[NE] = off;
        int nt = 0;
        for (int e = 0; e < NE; ++e)
            for (int s = 0; s < cnt[e]; s += BM) { tileE[nt] = e; tileRow[nt] = offsets[e] + s; ++nt; }
        *numTiles = nt;
    }
}

// ---------------- scatter tokens into expert-grouped row lists ----------------
__global__ __launch_bounds__(256) void scatter_kernel(
    const float* __restrict__ tidx, const float* __restrict__ tprob,
    const int* __restrict__ offsets, int* __restrict__ cursor,
    int* __restrict__ rowToken, float* __restrict__ rowProb)
{
    int t = blockIdx.x * 256 + threadIdx.x;
    if (t >= T_TOKENS) return;
#pragma unroll
    for (int k = 0; k < TOPK_; ++k) {
        int e = (int)tidx[t * 2 + k];
        float p = tprob[t * 2 + k];
        int pos = atomicAdd(&cursor[e], 1);
        int r = offsets[e] + pos;
        rowToken[r] = t;
        rowProb[r] = p;
    }
}

// ---------------- pass 1: h = gelu(Xg @ W1 + b1) ----------------
__global__ __launch_bounds__(256) void ffn1_kernel(
    const bf16_t* __restrict__ Xb, const bf16_t* __restrict__ W1T, const float* __restrict__ b1,
    const int* __restrict__ tileE, const int* __restrict__ tileRow, const int* __restrict__ numTiles,
    const int* __restrict__ offsets, const int* __restrict__ rowToken,
    bf16_t* __restrict__ h, int hc_base, int hc_len)
{
    int tile = blockIdx.x;
    if (tile >= *numTiles) return;
    int e = tileE[tile];
    int row0 = tileRow[tile];
    int rend = offsets[e + 1];
    int n0 = blockIdx.y * BN;
    int nglob = hc_base + n0;

    __shared__ __align__(16) char As[BM * BK * 2];   // 16 KB, rows of 128B
    __shared__ __align__(16) char Bs[BN * BK * 2];

    int tid = threadIdx.x;
    int lane = tid & 63;
    int wid = tid >> 6;
    int wr = (wid >> 1) * 64;
    int wc = (wid & 1) * 64;

    // staging geometry: issue i covers rows 32i..32i+31; thread t -> row 32i+(t>>3),
    // 16B chunk (t&7), source chunk XOR'd so swizzled read returns linear K
    int srow = tid >> 3;                           // 0..31
    int xc = (((tid & 7) ^ (srow & 7)) << 4);      // source byte offset within 128B row
    const char* gA[4];
    const char* gB[4];
#pragma unroll
    for (int i = 0; i < 4; ++i) {
        int rl = 32 * i + srow;
        int gr = row0 + rl; if (gr > NROWS - 1) gr = NROWS - 1;
        int tok = rowToken[gr];
        gA[i] = (const char*)(Xb + (size_t)tok * DIMD) + xc;
        gB[i] = (const char*)(W1T + ((size_t)e * HIDDEN + nglob + rl) * DIMD) + xc;
    }
    char* dA = As + wid * 1024;
    char* dB = Bs + wid * 1024;

    f32x4 acc[4][4];
#pragma unroll
    for (int i = 0; i < 4; ++i)
#pragma unroll
        for (int j = 0; j < 4; ++j) acc[i][j] = f32x4{0.f, 0.f, 0.f, 0.f};

    for (int k0 = 0; k0 < DIMD; k0 += BK) {
        int kb = k0 * 2;
#pragma unroll
        for (int i = 0; i < 4; ++i) {
            glds16(gA[i] + kb, dA + i * 4096);
            glds16(gB[i] + kb, dB + i * 4096);
        }
        __syncthreads();
#pragma unroll
        for (int ks = 0; ks < BK; ks += 32) {
            int kk = ks + (lane >> 4) * 8;
            int rr = lane & 15;
            bf16x8 af[4], bv[4];
#pragma unroll
            for (int m = 0; m < 4; ++m) af[m] = ldfrag(As, wr + m * 16 + rr, kk);
#pragma unroll
            for (int n = 0; n < 4; ++n) bv[n] = ldfrag(Bs, wc + n * 16 + rr, kk);
#pragma unroll
            for (int m = 0; m < 4; ++m)
#pragma unroll
                for (int n = 0; n < 4; ++n)
                    acc[m][n] = __builtin_amdgcn_mfma_f32_16x16x32_bf16(af[m], bv[n], acc[m][n], 0, 0, 0);
        }
        __syncthreads();
    }

    int crow = (lane >> 4) * 4;
    int ccol = lane & 15;
#pragma unroll
    for (int m = 0; m < 4; ++m) {
#pragma unroll
        for (int n = 0; n < 4; ++n) {
            int col = wc + n * 16 + ccol;
            float bias = b1[e * HIDDEN + nglob + col];
#pragma unroll
            for (int r = 0; r < 4; ++r) {
                int row = row0 + wr + m * 16 + crow + r;
                if (row < rend) {
                    float v = acc[m][n][r] + bias;
                    float g = 0.5f * v * (1.0f + erff(v * 0.70710678118654752f));
                    h[(size_t)row * hc_len + n0 + col] = (bf16_t)g;
                }
            }
        }
    }
}

// ---------------- pass 2: mixed += p * (Hg @ W2 + b2) ----------------
__global__ __launch_bounds__(256) void ffn2_kernel(
    const bf16_t* __restrict__ h, const bf16_t* __restrict__ W2T, const float* __restrict__ b2,
    const int* __restrict__ tileE, const int* __restrict__ tileRow, const int* __restrict__ numTiles,
    const int* __restrict__ offsets, const int* __restrict__ rowToken, const float* __restrict__ rowProb,
    float* __restrict__ mixed, int hc_base, int hc_len, int add_bias)
{
    int tile = blockIdx.x;
    if (tile >= *numTiles) return;
    int e = tileE[tile];
    int row0 = tileRow[tile];
    int rend = offsets[e + 1];
    int n0 = blockIdx.y * BN;

    __shared__ __align__(16) char As[BM * BK * 2];
    __shared__ __align__(16) char Bs[BN * BK * 2];

    int tid = threadIdx.x;
    int lane = tid & 63;
    int wid = tid >> 6;
    int wr = (wid >> 1) * 64;
    int wc = (wid & 1) * 64;

    int srow = tid >> 3;
    int xc = (((tid & 7) ^ (srow & 7)) << 4);
    const char* gA[4];
    const char* gB[4];
#pragma unroll
    for (int i = 0; i < 4; ++i) {
        int rl = 32 * i + srow;
        int gr = row0 + rl; if (gr > NROWS - 1) gr = NROWS - 1;
        gA[i] = (const char*)(h + (size_t)gr * hc_len) + xc;
        gB[i] = (const char*)(W2T + ((size_t)e * DIMD + n0 + rl) * HIDDEN + hc_base) + xc;
    }
    char* dA = As + wid * 1024;
    char* dB = Bs + wid * 1024;

    f32x4 acc[4][4];
#pragma unroll
    for (int i = 0; i < 4; ++i)
#pragma unroll
        for (int j = 0; j < 4; ++j) acc[i][j] = f32x4{0.f, 0.f, 0.f, 0.f};

    for (int k0 = 0; k0 < hc_len; k0 += BK) {
        int kb = k0 * 2;
#pragma unroll
        for (int i = 0; i < 4; ++i) {
            glds16(gA[i] + kb, dA + i * 4096);
            glds16(gB[i] + kb, dB + i * 4096);
        }
        __syncthreads();
#pragma unroll
        for (int ks = 0; ks < BK; ks += 32) {
            int kk = ks + (lane >> 4) * 8;
            int rr = lane & 15;
            bf16x8 af[4], bv[4];
#pragma unroll
            for (int m = 0; m < 4; ++m) af[m] = ldfrag(As, wr + m * 16 + rr, kk);
#pragma unroll
            for (int n = 0; n < 4; ++n) bv[n] = ldfrag(Bs, wc + n * 16 + rr, kk);
#pragma unroll
            for (int m = 0; m < 4; ++m)
#pragma unroll
                for (int n = 0; n < 4; ++n)
                    acc[m][n] = __builtin_amdgcn_mfma_f32_16x16x32_bf16(af[m], bv[n], acc[m][n], 0, 0, 0);
        }
        __syncthreads();
    }

    int crow = (lane >> 4) * 4;
    int ccol = lane & 15;
#pragma unroll
    for (int m = 0; m < 4; ++m) {
#pragma unroll
        for (int n = 0; n < 4; ++n) {
            int col = wc + n * 16 + ccol;
            int dcol = n0 + col;
            float bias = add_bias ? b2[e * DIMD + dcol] : 0.f;
#pragma unroll
            for (int r = 0; r < 4; ++r) {
                int row = row0 + wr + m * 16 + crow + r;
                if (row < rend) {
                    float v = acc[m][n][r] + bias;
                    float p = rowProb[row];
                    int tok = rowToken[row];
                    atomicAdd(&mixed[(size_t)tok * DIMD + dcol], p * v);
                }
            }
        }
    }
}

extern "C" void kernel_launch(void* const* d_in, const int* in_sizes, int n_in,
                              void* d_out, int out_size, void* d_ws, size_t ws_size,
                              hipStream_t stream)
{
    const float* x  = (const float*)d_in[0];
    const float* Wr = (const float*)d_in[1];
    const float* br = (const float*)d_in[2];
    const float* W1 = (const float*)d_in[3];
    const float* b1 = (const float*)d_in[4];
    const float* W2 = (const float*)d_in[5];
    const float* b2 = (const float*)d_in[6];

    float* out = (float*)d_out;
    float* mixed  = out;                                   // [8192][1024]
    float* logits = out + (size_t)T_TOKENS * DIMD;
    float* probs  = logits + T_TOKENS * NE;
    float* tidx   = probs + T_TOKENS * NE;
    float* tprob  = tidx + T_TOKENS * TOPK_;

    char* p = (char*)d_ws;
    auto alloc = [&](size_t bytes) { char* r = p; p += (bytes + 255) & ~255ull; return r; };
    int*    cnt      = (int*)alloc(NE * 4);
    int*    offsets  = (int*)alloc((NE + 1) * 4);
    int*    cursor   = (int*)alloc(NE * 4);
    int*    numTiles = (int*)alloc(4);
    int*    tileE    = (int*)alloc(MAXTILES * 4);
    int*    tileRow  = (int*)alloc(MAXTILES * 4);
    int*    rowToken = (int*)alloc(NROWS * 4);
    float*  rowProb  = (float*)alloc(NROWS * 4);
    bf16_t* W1T      = (bf16_t*)alloc((size_t)NE * HIDDEN * DIMD * 2);
    bf16_t* W2T      = (bf16_t*)alloc((size_t)NE * DIMD * HIDDEN * 2);
    bf16_t* Xb       = (bf16_t*)alloc((size_t)T_TOKENS * DIMD * 2);
    size_t used = (size_t)(p - (char*)d_ws);
    size_t remain = ws_size > used ? ws_size - used : 0;
    int hc = HIDDEN;
    while (hc > 512 && (size_t)NROWS * hc * 2 > remain) hc >>= 1;
    bf16_t* hbuf = (bf16_t*)alloc((size_t)NROWS * hc * 2);

    hipMemsetAsync(mixed, 0, (size_t)T_TOKENS * DIMD * 4, stream);
    hipMemsetAsync(cnt, 0, NE * 4, stream);

    router_kernel<<<T_TOKENS / 4, 256, 0, stream>>>(x, Wr, br, logits, probs, tidx, tprob, cnt);
    xconv_kernel<<<(T_TOKENS * DIMD / 8 + 255) / 256, 256, 0, stream>>>(x, Xb);
    transpose_kernel<<<dim3(DIMD / 32, HIDDEN / 32, NE), 256, 0, stream>>>(W1, W1T, DIMD, HIDDEN);
    transpose_kernel<<<dim3(HIDDEN / 32, DIMD / 32, NE), 256, 0, stream>>>(W2, W2T, HIDDEN, DIMD);
    prefix_kernel<<<1, 64, 0, stream>>>(cnt, offsets, cursor, tileE, tileRow, numTiles);
    scatter_kernel<<<T_TOKENS / 256, 256, 0, stream>>>(tidx, tprob, offsets, cursor, rowToken, rowProb);

    for (int c0 = 0; c0 < HIDDEN; c0 += hc) {
        ffn1_kernel<<<dim3(MAXTILES, hc / BN), 256, 0, stream>>>(
            Xb, W1T, b1, tileE, tileRow, numTiles, offsets, rowToken, hbuf, c0, hc);
        ffn2_kernel<<<dim3(MAXTILES, DIMD / BN), 256, 0, stream>>>(
            hbuf, W2T, b2, tileE, tileRow, numTiles, offsets, rowToken, rowProb,
            mixed, c0, hc, c0 == 0 ? 1 : 0);
    }
}